// Round 9
// baseline (577.553 us; speedup 1.0000x reference)
//
#include <hip/hip_runtime.h>

#define SEQ   1024
#define BATCH 8192
#define HID   50
#define BT    16           // batch rows per block (MFMA N)
#define CHS   16           // steps per x chunk
#define NCH   (SEQ/CHS)

typedef _Float16 half8 __attribute__((ext_vector_type(8)));
typedef float    f32x4 __attribute__((ext_vector_type(4)));

// state-fragment slot for value (k, batch b): layout [kh][grpk][b][i]
__device__ __forceinline__ int bslot(int k, int b){
  return (k >> 5)*512 + ((k & 31) >> 3)*128 + b*8 + (k & 7);
}

#define MFMA16(A,B,C) __builtin_amdgcn_mfma_f32_16x16x32_f16(A,B,C,0,0,0)

// chunk cg -> 3 regs; flat f = tid + 256u; step s = f/48, elem e = f%48
#define XLD(cg) {                                                          \
    const int f1 = tid + 256, f2 = tid + 512;                              \
    const int s0_ = (tid*683) >> 15, s1_ = (f1*683) >> 15,                 \
              s2_ = (f2*683) >> 15;                                        \
    xr0 = x[(size_t)(((cg)*CHS + s0_)*BATCH + b0)*3 + (tid - 48*s0_)];     \
    xr1 = x[(size_t)(((cg)*CHS + s1_)*BATCH + b0)*3 + (f1  - 48*s1_)];     \
    xr2 = x[(size_t)(((cg)*CHS + s2_)*BATCH + b0)*3 + (f2  - 48*s2_)]; }

// commit the 3 chunk regs (fp32) into the xs strip (fp16), buffer bf
#define XCOMMIT(bf) {                                                      \
    const int f1 = tid + 256, f2 = tid + 512;                              \
    const int s0_ = (tid*683) >> 15, s1_ = (f1*683) >> 15,                 \
              s2_ = (f2*683) >> 15;                                        \
    const int r0_ = tid - 48*s0_, r1_ = f1 - 48*s1_, r2_ = f2 - 48*s2_;    \
    const int b0_ = (r0_*171) >> 9, b1_ = (r1_*171) >> 9,                  \
              b2_ = (r2_*171) >> 9;                                        \
    xs[bf][s0_][b0_][r0_ - 3*b0_] = (_Float16)xr0;                         \
    xs[bf][s1_][b1_][r1_ - 3*b1_] = (_Float16)xr1;                         \
    xs[bf][s2_][b2_][r2_ - 3*b2_] = (_Float16)xr2; }

// Lean LSTM cell (validated r7/r8): acc[0..3] = pre-scaled (i,f,g,o);
// C tracks 2*log2e*c.  5 exp2 + 2 rcp per item.
#define ELEM(acc, C, bq, slot) {                                              \
    const float Ei = __builtin_amdgcn_exp2f((acc)[0]);                        \
    const float Ef = __builtin_amdgcn_exp2f((acc)[1]);                        \
    const float Eg = __builtin_amdgcn_exp2f(fminf((acc)[2], 60.0f));          \
    const float Eo = __builtin_amdgcn_exp2f((acc)[3]);                        \
    const float di = 1.0f + Ei, df = 1.0f + Ef, dg = 1.0f + Eg;               \
    const float digg = di*dg;                                                 \
    const float r1 = __builtin_amdgcn_rcpf(digg*df);                          \
    const float t2 = __builtin_fmaf(Eg, 2.88539008177792f,                    \
                                    -2.88539008177792f);                      \
    const float num = __builtin_fmaf(C, digg, t2*df);                         \
    C = num*r1;                                                               \
    const float Ec = __builtin_amdgcn_exp2f(fminf(C, 80.0f));                 \
    const float r2 = __builtin_amdgcn_rcpf((1.0f+Eo)*(1.0f+Ec));              \
    (bq)[slot] = (_Float16)((Ec - 1.0f)*r2); }

__global__ __launch_bounds__(256, 2)
void lstm_ph(const float* __restrict__ x,
             const float* __restrict__ W_ih,
             const float* __restrict__ W_hh,
             const float* __restrict__ b_ih,
             const float* __restrict__ b_hh,
             const float* __restrict__ fc_w,
             const float* __restrict__ fc_b,
             float* __restrict__ out)
{
  // double-buffered h-state fragment in MFMA-B layout (pure h, 4 KB)
  __shared__ _Float16 Bst[2][1024];
  // per-step x strip: [buf][step][b][(x0,x1,x2,1.0)] halfs (4 KB)
  __shared__ _Float16 xs[2][CHS][16][4];

  const int tid  = threadIdx.x;
  const int w    = tid >> 6;          // 0..3
  const int lane = tid & 63;
  const int r16  = lane & 15;         // batch col
  const int grp  = lane >> 4;
  const int b0   = blockIdx.x * BT;
  const float L2E = 1.44269504088896f;

  // anti-correlated tile maps: odd blocks reverse the wave->tile assignment
  const int  vw = (blockIdx.x & 1) ? (3 - w) : w;
  const int  nt = (vw == 3) ? 4 : 3;  // wave vw==3 also owns tile 12

  // ---- A fragments (weights) for tiles {vw, vw+4, vw+8} (+12) ----
  // rows permuted c=4j+gate, pre-scaled: i,f,o by -log2e; g by +2log2e
  half8 Af[4][2];
  #pragma unroll
  for (int it = 0; it < 4; ++it) {
    const int tile = (it < 3) ? (vw + 4*it) : 12;
    #pragma unroll
    for (int kh = 0; kh < 2; ++kh) {
      half8 f;
      #pragma unroll
      for (int i = 0; i < 8; ++i) {
        const int k = kh*32 + grp*8 + i;
        const int c = tile*16 + r16;
        float wv = 0.0f;
        if (c < 4*HID) {
          const int j = c >> 2, gi = c & 3;
          const int go = gi*HID + j;                     // i,f,g,o row order
          const float sc = (gi == 2) ? (2.0f*L2E) : (-L2E);
          if (k < HID)      wv = W_hh[go*HID + k] * sc;
          else if (k < 53)  wv = W_ih[go*3 + (k-50)] * sc;
          else if (k == 53) wv = (b_ih[go] + b_hh[go]) * sc;
        }
        f[i] = (_Float16)wv;
      }
      Af[it][kh] = f;
    }
  }

  // h-write slots: item (b=r16, j=tile*4+grp); tile12 valid only grp<2
  int wsl[4];
  #pragma unroll
  for (int it = 0; it < 4; ++it) {
    const int tile = (it < 3) ? (vw + 4*it) : 12;
    const int j = tile*4 + grp;
    wsl[it] = bslot((j < HID) ? j : 0, r16);
  }

  // ---- init: zero both h buffers; set xs bias slots e=3 to 1.0 ----
  #pragma unroll
  for (int i = 0; i < 4; ++i) ((unsigned*)Bst)[tid + 256*i] = 0u;
  #pragma unroll
  for (int i2 = 0; i2 < 2; ++i2) {
    const int i = tid + 256*i2;
    xs[i >> 8][(i >> 4) & 15][i & 15][3] = (_Float16)1.0f;
  }

  // ---- x prologue: chunk 0 -> xs[0]; chunk 1 -> regs ----
  float xr0, xr1, xr2;
  XLD(0);
  XCOMMIT(0);
  XLD(1);
  __syncthreads();

  // phase stagger: odd blocks start ~256 cycles late and stay anti-phase
  if (blockIdx.x & 1) __builtin_amdgcn_s_sleep(4);

  float cs[4] = {0.f, 0.f, 0.f, 0.f};
  const _Float16* xsp = &xs[0][0][0][0];

  auto STEP = [&](int tsv, int p, int q) {
    // state reads + x-strip read fly together; x patched into regs
    const half8 s0 = *(const half8*)&Bst[p][lane*8];
    uint4 s1d = *(const uint4*)&Bst[p][512 + lane*8];
    const uint2 xd = *(const uint2*)&xsp[tsv*64 + r16*4];
    if (grp == 2) { s1d.y = xd.x; s1d.z = xd.y; }   // k=50..53 <- (x,1.0)
    const half8 s1 = __builtin_bit_cast(half8, s1d);
    f32x4 a[4];
    #pragma unroll
    for (int it = 0; it < 4; ++it) if (it < nt) {
      f32x4 z = {0.f, 0.f, 0.f, 0.f};
      z = MFMA16(Af[it][0], s0, z);
      a[it] = MFMA16(Af[it][1], s1, z);
    }
    _Float16* bq = &Bst[q][0];
    #pragma unroll
    for (int it = 0; it < 3; ++it) ELEM(a[it], cs[it], bq, wsl[it]);
    if (nt == 4 && grp < 2) ELEM(a[3], cs[3], bq, wsl[3]);
    // LDS-only barrier: do NOT drain vmcnt (x prefetch stays in flight)
    asm volatile("s_waitcnt lgkmcnt(0)\n\ts_barrier" ::: "memory");
  };

  #pragma unroll 1
  for (int tc = 0; tc < NCH; ++tc) {
    if (tc + 1 < NCH) {
      XCOMMIT((tc + 1) & 1);          // commit chunk tc+1 (in regs)
      if (tc + 2 < NCH) { XLD(tc+2); }
    }
    xsp = &xs[tc & 1][0][0][0];
    #pragma unroll 2
    for (int ts = 0; ts < CHS; ts += 2) {
      STEP(ts,     0, 1);
      STEP(ts + 1, 1, 0);
    }
  }

  // ---- epilogue: h_1024 sits in Bst[0] ----
  __syncthreads();
  if (tid < BT) {
    float s = fc_b[0];
    #pragma unroll
    for (int j = 0; j < HID; ++j)
      s += fc_w[j] * (float)Bst[0][bslot(j, tid)];
    out[b0 + tid] = s;
  }
}

extern "C" void kernel_launch(void* const* d_in, const int* in_sizes, int n_in,
                              void* d_out, int out_size, void* d_ws, size_t ws_size,
                              hipStream_t stream)
{
  const float* x    = (const float*)d_in[0];
  const float* W_ih = (const float*)d_in[1];
  const float* W_hh = (const float*)d_in[2];
  const float* b_ih = (const float*)d_in[3];
  const float* b_hh = (const float*)d_in[4];
  const float* fc_w = (const float*)d_in[5];
  const float* fc_b = (const float*)d_in[6];
  lstm_ph<<<BATCH/BT, 256, 0, stream>>>(x, W_ih, W_hh, b_ih, b_hh,
                                        fc_w, fc_b, (float*)d_out);
}